// Round 8
// baseline (74.331 us; speedup 1.0000x reference)
//
#include <hip/hip_runtime.h>
#include <hip/hip_bf16.h>
#include <stdint.h>

#define EMBED  128
#define HIDDEN 512
#define TB     64    // tokens per mlp block
#define CAP    32    // bucket capacity per vocab row (Poisson lambda=4; P(>32)~1e-19)

typedef __attribute__((ext_vector_type(8))) short short8v;   // 8 bf16 = 4 VGPR
typedef __attribute__((ext_vector_type(4))) float f32x4;

__device__ __forceinline__ ushort f2bf(float f) {
    uint32_t b = __float_as_uint(f);
    uint32_t r = (b + 0x7FFFu + ((b >> 16) & 1u)) >> 16;
    return (ushort)r;
}

__device__ __forceinline__ float gelu_fast(float x) {
    // 0.5x(1+tanh(u)) == x - x/(exp(2u)+1),  u = 0.79788456(x + 0.044715x^3)
    float x2 = x * x;
    float u  = x * fmaf(0.035677408136f, x2, 0.7978845608f);
    float t  = __expf(2.0f * u);
    return x - x * __frcp_rn(t + 1.0f);
}

// ---------------------------------------------------------------------------
// K1: blocks [0,128) weight transpose+cast; blocks [128,...) zero cnt.
// ---------------------------------------------------------------------------
__global__ __launch_bounds__(256)
void prep_kernel(const float* __restrict__ w1, const float* __restrict__ w2,
                 ushort* __restrict__ W1t, ushort* __restrict__ W2t,
                 int* __restrict__ cnt, int vocab) {
    __shared__ float T[32][33];
    int b = blockIdx.x;
    int t = threadIdx.x;
    if (b < 128) {
        const float* in; ushort* outp; int inCols, outCols, tr, tc;
        if (b < 64) {            // W1: [128][512] -> W1t [512][128]
            in = w1; outp = W1t; inCols = 512; outCols = 128;
            tr = b >> 4; tc = b & 15;
        } else {                 // W2: [512][128] -> W2t [128][512]
            int b2 = b - 64;
            in = w2; outp = W2t; inCols = 128; outCols = 512;
            tr = b2 >> 2; tc = b2 & 3;
        }
        int r  = t >> 3;
        int c4 = (t & 7) * 4;
        float4 v = *(const float4*)&in[(size_t)(tr * 32 + r) * inCols + tc * 32 + c4];
        T[c4 + 0][r] = v.x; T[c4 + 1][r] = v.y; T[c4 + 2][r] = v.z; T[c4 + 3][r] = v.w;
        __syncthreads();
        ushort o[4];
        #pragma unroll
        for (int i = 0; i < 4; ++i) o[i] = f2bf(T[r][c4 + i]);
        *(ushort4*)&outp[(size_t)(tc * 32 + r) * outCols + tr * 32 + c4] = *(ushort4*)o;
    } else {
        int i = (b - 128) * 256 + t;
        if (i < vocab) cnt[i] = 0;
    }
}

// ---------------------------------------------------------------------------
// K2: bucket ALL bloom entries into CSR
// ---------------------------------------------------------------------------
__global__ __launch_bounds__(256)
void bucket_kernel(const int* __restrict__ bi, const int* __restrict__ bj,
                   int* __restrict__ cnt, int* __restrict__ csr, int nk) {
    int k = blockIdx.x * blockDim.x + threadIdx.x;
    if (k >= nk) return;
    int i = bi[k];
    int slot = atomicAdd(&cnt[i], 1);
    if (slot < CAP) csr[(size_t)i * CAP + slot] = bj[k];
}

// ---------------------------------------------------------------------------
// K3: per-token-position aggregation (one wave per position, no barriers):
//   aggbf[idx] = bf16(0.5 * sum_{j in csr[tokens[idx]]} table[j])
// 32768 waves -> full occupancy; scattered 512B table reads latency-hidden.
// ---------------------------------------------------------------------------
__global__ __launch_bounds__(256)
void agg_kernel(const int*   __restrict__ tokens,
                const float* __restrict__ table,
                const int*   __restrict__ cnt,
                const int*   __restrict__ csr,
                ushort*      __restrict__ aggbf, int ntok) {
    int wid  = (blockIdx.x * blockDim.x + threadIdx.x) >> 6;
    int lane = threadIdx.x & 63;
    if (wid >= ntok) return;
    int tok = tokens[wid];
    int m = min(cnt[tok], CAP);
    const int* jrow = csr + (size_t)tok * CAP;
    float a0 = 0.f, a1 = 0.f;
    for (int e = 0; e < m; ++e) {
        int j = jrow[e];
        float2 v = *(const float2*)&table[(size_t)j * EMBED + lane * 2];
        a0 += v.x; a1 += v.y;
    }
    ushort2 o;
    o.x = f2bf(0.5f * a0);
    o.y = f2bf(0.5f * a1);
    *(ushort2*)&aggbf[(size_t)wid * EMBED + lane * 2] = o;
}

// ---------------------------------------------------------------------------
// K4: bf16-MFMA MLP. X rows are LINEAR rows of aggbf (position-indexed).
// 512 threads = 8 waves, 64 tokens/block, 512 blocks.
// GEMM1: wave w -> hidden cols [w*64, w*64+64)   acc 4x4 f32x4
// GEMM2: wave w -> out    cols [w*16, w*16+16)   acc 4   f32x4
// ---------------------------------------------------------------------------
__global__ __launch_bounds__(512)
void mlp_mfma_kernel(const ushort* __restrict__ aggbf,
                     const ushort* __restrict__ W1t,   // [512][128] bf16
                     const ushort* __restrict__ W2t,   // [128][512] bf16
                     const float*  __restrict__ b1,
                     const float*  __restrict__ b2,
                     float*        __restrict__ out) {
    __shared__ ushort Xs[TB * EMBED];    // 16 KB, XOR-swizzled (granule16 ^= row&7)
    __shared__ ushort Hs[TB * HIDDEN];   // 64 KB, XOR-swizzled

    const int t    = threadIdx.x;
    const int lane = t & 63;
    const int wv   = t >> 6;             // 0..7
    const int base = blockIdx.x * TB;
    const int l15  = lane & 15;
    const int lhi  = lane >> 4;          // 0..3

    // ---- stage X: linear copy of aggbf rows [base, base+64) ----
    {
        int r  = t >> 3;                 // 0..63
        int g0 = (t & 7) * 2;            // two 8-elem granules per thread
        const ushort* src = aggbf + (size_t)(base + r) * EMBED;
        #pragma unroll
        for (int h = 0; h < 2; ++h) {
            int g = g0 + h;
            short8v v = *(const short8v*)(src + g * 8);
            *(short8v*)&Xs[r * EMBED + (g ^ (r & 7)) * 8] = v;
        }
    }
    __syncthreads();

    // ---- GEMM1: H[64][64 per wave] = X @ W1 ----
    f32x4 acc1[4][4];
    #pragma unroll
    for (int n = 0; n < 4; ++n) {
        float bv = b1[wv * 64 + n * 16 + l15];
        #pragma unroll
        for (int m = 0; m < 4; ++m) acc1[m][n] = (f32x4){bv, bv, bv, bv};
    }

    #pragma unroll
    for (int kk = 0; kk < EMBED / 32; ++kk) {       // 4 k-steps
        short8v a[4];
        #pragma unroll
        for (int m = 0; m < 4; ++m) {
            int r = m * 16 + l15;
            int g = (kk * 4 + lhi) ^ (r & 7);
            a[m] = *(const short8v*)&Xs[r * EMBED + g * 8];
        }
        #pragma unroll
        for (int n = 0; n < 4; ++n) {
            int col = wv * 64 + n * 16 + l15;
            short8v b = *(const short8v*)(W1t + (size_t)col * EMBED + kk * 32 + lhi * 8);
            #pragma unroll
            for (int m = 0; m < 4; ++m)
                acc1[m][n] = __builtin_amdgcn_mfma_f32_16x16x32_bf16(a[m], b, acc1[m][n], 0, 0, 0);
        }
    }

    // ---- gelu -> bf16 -> swizzled Hs ----
    #pragma unroll
    for (int n = 0; n < 4; ++n) {
        int col = wv * 64 + n * 16 + l15;
        #pragma unroll
        for (int m = 0; m < 4; ++m)
            #pragma unroll
            for (int q = 0; q < 4; ++q) {
                int row = m * 16 + lhi * 4 + q;
                float hv = gelu_fast(acc1[m][n][q]);
                int g = (col >> 3) ^ (row & 7);
                Hs[row * HIDDEN + g * 8 + (col & 7)] = f2bf(hv);
            }
    }
    __syncthreads();

    // ---- GEMM2: out[64][16 per wave] = H @ W2 ----
    f32x4 acc2[4];
    {
        float bv = b2[wv * 16 + l15];
        #pragma unroll
        for (int m = 0; m < 4; ++m) acc2[m] = (f32x4){bv, bv, bv, bv};
    }
    #pragma unroll
    for (int kk = 0; kk < HIDDEN / 32; ++kk) {      // 16 k-steps
        short8v a[4];
        #pragma unroll
        for (int m = 0; m < 4; ++m) {
            int r = m * 16 + l15;
            int g = (kk * 4 + lhi) ^ (r & 7);
            a[m] = *(const short8v*)&Hs[r * HIDDEN + g * 8];
        }
        int col = wv * 16 + l15;
        short8v b = *(const short8v*)(W2t + (size_t)col * HIDDEN + kk * 32 + lhi * 8);
        #pragma unroll
        for (int m = 0; m < 4; ++m)
            acc2[m] = __builtin_amdgcn_mfma_f32_16x16x32_bf16(a[m], b, acc2[m], 0, 0, 0);
    }

    // ---- store ----
    #pragma unroll
    for (int m = 0; m < 4; ++m)
        #pragma unroll
        for (int q = 0; q < 4; ++q) {
            int row = m * 16 + lhi * 4 + q;
            out[(size_t)(base + row) * EMBED + wv * 16 + l15] = acc2[m][q];
        }
}

// ---------------------------------------------------------------------------
extern "C" void kernel_launch(void* const* d_in, const int* in_sizes, int n_in,
                              void* d_out, int out_size, void* d_ws, size_t ws_size,
                              hipStream_t stream) {
    const int*   tokens = (const int*)  d_in[0];
    const float* table  = (const float*)d_in[1];
    const int*   bi     = (const int*)  d_in[2];
    const int*   bj     = (const int*)  d_in[3];
    const float* w1     = (const float*)d_in[4];
    const float* b1     = (const float*)d_in[5];
    const float* w2     = (const float*)d_in[6];
    const float* b2     = (const float*)d_in[7];
    float* out = (float*)d_out;

    const int vocab = in_sizes[1] / EMBED;   // 50257
    const int nk    = in_sizes[2];           // 4 * vocab
    const int ntok  = in_sizes[0];           // 32768

    // ---- workspace layout (~15.3 MB) ----
    char* ws = (char*)d_ws;
    size_t off = 0;
    auto alloc = [&](size_t b) { size_t o = off; off += (b + 255) & ~(size_t)255; return o; };
    ushort* W1t   = (ushort*)(ws + alloc((size_t)EMBED * HIDDEN * 2));
    ushort* W2t   = (ushort*)(ws + alloc((size_t)EMBED * HIDDEN * 2));
    ushort* aggbf = (ushort*)(ws + alloc((size_t)ntok * EMBED * 2));
    int*    csr   = (int*)   (ws + alloc((size_t)vocab * CAP * 4));
    int*    cnt   = (int*)   (ws + alloc((size_t)vocab * 4));

    int zeroBlocks = (vocab + 255) / 256;                         // 197
    prep_kernel<<<128 + zeroBlocks, 256, 0, stream>>>(w1, w2, W1t, W2t, cnt, vocab);

    bucket_kernel<<<(nk + 255) / 256, 256, 0, stream>>>(bi, bj, cnt, csr, nk);

    agg_kernel<<<(ntok * 64) / 256, 256, 0, stream>>>(tokens, table, cnt, csr, aggbf, ntok);

    mlp_mfma_kernel<<<ntok / TB, 512, 0, stream>>>(aggbf, W1t, W2t, b1, b2, out);
}

// Round 9
// 57.763 us; speedup vs baseline: 1.2868x; 1.2868x over previous
//
#include <hip/hip_runtime.h>
#include <hip/hip_bf16.h>
#include <stdint.h>

#define EMBED  128
#define HIDDEN 512
#define TB     64    // tokens per mlp block
#define HHALF  256   // hidden cols per pass (2 passes)
#define CAP    32    // bucket capacity per vocab row (Poisson lambda=4; P(>32)~1e-19)

typedef __attribute__((ext_vector_type(8))) short short8v;   // 8 bf16 = 4 VGPR
typedef __attribute__((ext_vector_type(4))) float f32x4;

__device__ __forceinline__ ushort f2bf(float f) {
    uint32_t b = __float_as_uint(f);
    uint32_t r = (b + 0x7FFFu + ((b >> 16) & 1u)) >> 16;
    return (ushort)r;
}

__device__ __forceinline__ float gelu_fast(float x) {
    // 0.5x(1+tanh(u)) == x - x/(exp(2u)+1),  u = 0.79788456(x + 0.044715x^3)
    float x2 = x * x;
    float u  = x * fmaf(0.035677408136f, x2, 0.7978845608f);
    float t  = __expf(2.0f * u);
    return x - x * __frcp_rn(t + 1.0f);
}

// ---------------------------------------------------------------------------
// K1: blocks [0,128) weight transpose+cast; blocks [128,...) zero cnt.
// ---------------------------------------------------------------------------
__global__ __launch_bounds__(256)
void prep_kernel(const float* __restrict__ w1, const float* __restrict__ w2,
                 ushort* __restrict__ W1t, ushort* __restrict__ W2t,
                 int* __restrict__ cnt, int vocab) {
    __shared__ float T[32][33];
    int b = blockIdx.x;
    int t = threadIdx.x;
    if (b < 128) {
        const float* in; ushort* outp; int inCols, outCols, tr, tc;
        if (b < 64) {            // W1: [128][512] -> W1t [512][128]
            in = w1; outp = W1t; inCols = 512; outCols = 128;
            tr = b >> 4; tc = b & 15;
        } else {                 // W2: [512][128] -> W2t [128][512]
            int b2 = b - 64;
            in = w2; outp = W2t; inCols = 128; outCols = 512;
            tr = b2 >> 2; tc = b2 & 3;
        }
        int r  = t >> 3;
        int c4 = (t & 7) * 4;
        float4 v = *(const float4*)&in[(size_t)(tr * 32 + r) * inCols + tc * 32 + c4];
        T[c4 + 0][r] = v.x; T[c4 + 1][r] = v.y; T[c4 + 2][r] = v.z; T[c4 + 3][r] = v.w;
        __syncthreads();
        ushort o[4];
        #pragma unroll
        for (int i = 0; i < 4; ++i) o[i] = f2bf(T[r][c4 + i]);
        *(ushort4*)&outp[(size_t)(tc * 32 + r) * outCols + tr * 32 + c4] = *(ushort4*)o;
    } else {
        int i = (b - 128) * 256 + t;
        if (i < vocab) cnt[i] = 0;
    }
}

// ---------------------------------------------------------------------------
// K2: bucket ALL bloom entries into CSR
// ---------------------------------------------------------------------------
__global__ __launch_bounds__(256)
void bucket_kernel(const int* __restrict__ bi, const int* __restrict__ bj,
                   int* __restrict__ cnt, int* __restrict__ csr, int nk) {
    int k = blockIdx.x * blockDim.x + threadIdx.x;
    if (k >= nk) return;
    int i = bi[k];
    int slot = atomicAdd(&cnt[i], 1);
    if (slot < CAP) csr[(size_t)i * CAP + slot] = bj[k];
}

// ---------------------------------------------------------------------------
// K3: fused bloom-gather + bf16-MFMA MLP, hidden processed in 2 halves.
// 512 threads = 8 waves, 64 tokens/block, 512 blocks. LDS 48 KB -> 3 blk/CU.
// Gather: masked unrolled 8 rows (MLP), rare tail loop for m>8.
// GEMM1 half: wave w -> hid cols [h*256+w*32, +32)   acc 4x2 f32x4
// GEMM2 half: wave w -> out cols [w*16, +16)          acc 4   f32x4 (persists)
// ---------------------------------------------------------------------------
__global__ __launch_bounds__(512)
void mlp_mfma_kernel(const int*    __restrict__ tokens,
                     const float*  __restrict__ table,
                     const int*    __restrict__ cnt,
                     const int*    __restrict__ csr,
                     const ushort* __restrict__ W1t,   // [512][128] bf16
                     const ushort* __restrict__ W2t,   // [128][512] bf16
                     const float*  __restrict__ b1,
                     const float*  __restrict__ b2,
                     float*        __restrict__ out) {
    __shared__ ushort Xs[TB * EMBED];    // 16 KB, XOR-swizzled (granule16 ^= row&7)
    __shared__ ushort Hs[TB * HHALF];    // 32 KB, XOR-swizzled

    const int t    = threadIdx.x;
    const int lane = t & 63;
    const int wv   = t >> 6;             // 0..7
    const int base = blockIdx.x * TB;
    const int l15  = lane & 15;
    const int lhi  = lane >> 4;          // 0..3

    // ---- X-stage: inline bloom aggregation, 8 threads/token, masked MLP-8 ----
    {
        int r    = t >> 3;               // 0..63
        int coff = (t & 7) * 16;         // 16 floats per thread
        int tok  = tokens[base + r];
        int m    = min(cnt[tok], CAP);
        const int* jrow = csr + (size_t)tok * CAP;
        f32x4 xa0 = {0.f,0.f,0.f,0.f}, xa1 = {0.f,0.f,0.f,0.f};
        f32x4 xa2 = {0.f,0.f,0.f,0.f}, xa3 = {0.f,0.f,0.f,0.f};
        #pragma unroll 2
        for (int e = 0; e < 8; ++e) {
            int j = (e < m) ? jrow[e] : 0;      // unconditional issue, masked add
            const float* trp = table + (size_t)j * EMBED + coff;
            float4 v0 = *(const float4*)(trp);
            float4 v1 = *(const float4*)(trp + 4);
            float4 v2 = *(const float4*)(trp + 8);
            float4 v3 = *(const float4*)(trp + 12);
            if (e < m) {
                xa0 += (f32x4){v0.x, v0.y, v0.z, v0.w};
                xa1 += (f32x4){v1.x, v1.y, v1.z, v1.w};
                xa2 += (f32x4){v2.x, v2.y, v2.z, v2.w};
                xa3 += (f32x4){v3.x, v3.y, v3.z, v3.w};
            }
        }
        for (int e = 8; e < m; ++e) {           // rare tail (P ~2%)
            int j = jrow[e];
            const float* trp = table + (size_t)j * EMBED + coff;
            float4 v0 = *(const float4*)(trp);
            float4 v1 = *(const float4*)(trp + 4);
            float4 v2 = *(const float4*)(trp + 8);
            float4 v3 = *(const float4*)(trp + 12);
            xa0 += (f32x4){v0.x, v0.y, v0.z, v0.w};
            xa1 += (f32x4){v1.x, v1.y, v1.z, v1.w};
            xa2 += (f32x4){v2.x, v2.y, v2.z, v2.w};
            xa3 += (f32x4){v3.x, v3.y, v3.z, v3.w};
        }
        ushort u[16];
        #pragma unroll
        for (int q = 0; q < 4; ++q) {
            u[q]      = f2bf(0.5f * xa0[q]);
            u[4 + q]  = f2bf(0.5f * xa1[q]);
            u[8 + q]  = f2bf(0.5f * xa2[q]);
            u[12 + q] = f2bf(0.5f * xa3[q]);
        }
        int g0 = (t & 7) * 2;
        #pragma unroll
        for (int h = 0; h < 2; ++h)
            *(short8v*)&Xs[r * EMBED + ((g0 + h) ^ (r & 7)) * 8] = *(short8v*)&u[h * 8];
    }
    __syncthreads();

    // ---- out accumulator persists across both hidden halves ----
    f32x4 acc2[4];
    {
        float bv = b2[wv * 16 + l15];
        #pragma unroll
        for (int m = 0; m < 4; ++m) acc2[m] = (f32x4){bv, bv, bv, bv};
    }

    #pragma unroll
    for (int h = 0; h < 2; ++h) {
        // ---- GEMM1 half: H[64][32 per wave] = X @ W1[:, h*256+wv*32 ...] ----
        f32x4 acc1[4][2];
        #pragma unroll
        for (int n = 0; n < 2; ++n) {
            float bv = b1[h * HHALF + wv * 32 + n * 16 + l15];
            #pragma unroll
            for (int m = 0; m < 4; ++m) acc1[m][n] = (f32x4){bv, bv, bv, bv};
        }
        #pragma unroll
        for (int kk = 0; kk < EMBED / 32; ++kk) {   // 4 k-steps
            short8v a[4];
            #pragma unroll
            for (int m = 0; m < 4; ++m) {
                int r = m * 16 + l15;
                int g = (kk * 4 + lhi) ^ (r & 7);
                a[m] = *(const short8v*)&Xs[r * EMBED + g * 8];
            }
            #pragma unroll
            for (int n = 0; n < 2; ++n) {
                int col = h * HHALF + wv * 32 + n * 16 + l15;
                short8v b = *(const short8v*)(W1t + (size_t)col * EMBED + kk * 32 + lhi * 8);
                #pragma unroll
                for (int m = 0; m < 4; ++m)
                    acc1[m][n] = __builtin_amdgcn_mfma_f32_16x16x32_bf16(a[m], b, acc1[m][n], 0, 0, 0);
            }
        }

        // ---- gelu -> bf16 -> swizzled Hs (cols within half: 0..255) ----
        #pragma unroll
        for (int n = 0; n < 2; ++n) {
            int colh = wv * 32 + n * 16 + l15;
            #pragma unroll
            for (int m = 0; m < 4; ++m)
                #pragma unroll
                for (int q = 0; q < 4; ++q) {
                    int row = m * 16 + lhi * 4 + q;
                    float hv = gelu_fast(acc1[m][n][q]);
                    int g = (colh >> 3) ^ (row & 7);
                    Hs[row * HHALF + g * 8 + (colh & 7)] = f2bf(hv);
                }
        }
        __syncthreads();

        // ---- GEMM2 half: acc2 += H_half @ W2[h*256 ...] ----
        #pragma unroll
        for (int kk = 0; kk < HHALF / 32; ++kk) {   // 8 k-steps
            short8v a[4];
            #pragma unroll
            for (int m = 0; m < 4; ++m) {
                int r = m * 16 + l15;
                int g = (kk * 4 + lhi) ^ (r & 7);
                a[m] = *(const short8v*)&Hs[r * HHALF + g * 8];
            }
            int col = wv * 16 + l15;
            short8v b = *(const short8v*)(W2t + (size_t)col * HIDDEN + h * HHALF + kk * 32 + lhi * 8);
            #pragma unroll
            for (int m = 0; m < 4; ++m)
                acc2[m] = __builtin_amdgcn_mfma_f32_16x16x32_bf16(a[m], b, acc2[m], 0, 0, 0);
        }
        __syncthreads();    // before next half overwrites Hs
    }

    // ---- store ----
    #pragma unroll
    for (int m = 0; m < 4; ++m)
        #pragma unroll
        for (int q = 0; q < 4; ++q) {
            int row = m * 16 + lhi * 4 + q;
            out[(size_t)(base + row) * EMBED + wv * 16 + l15] = acc2[m][q];
        }
}

// ---------------------------------------------------------------------------
extern "C" void kernel_launch(void* const* d_in, const int* in_sizes, int n_in,
                              void* d_out, int out_size, void* d_ws, size_t ws_size,
                              hipStream_t stream) {
    const int*   tokens = (const int*)  d_in[0];
    const float* table  = (const float*)d_in[1];
    const int*   bi     = (const int*)  d_in[2];
    const int*   bj     = (const int*)  d_in[3];
    const float* w1     = (const float*)d_in[4];
    const float* b1     = (const float*)d_in[5];
    const float* w2     = (const float*)d_in[6];
    const float* b2     = (const float*)d_in[7];
    float* out = (float*)d_out;

    const int vocab = in_sizes[1] / EMBED;   // 50257
    const int nk    = in_sizes[2];           // 4 * vocab
    const int ntok  = in_sizes[0];           // 32768

    // ---- workspace layout (~7 MB) ----
    char* ws = (char*)d_ws;
    size_t off = 0;
    auto alloc = [&](size_t b) { size_t o = off; off += (b + 255) & ~(size_t)255; return o; };
    ushort* W1t = (ushort*)(ws + alloc((size_t)EMBED * HIDDEN * 2));
    ushort* W2t = (ushort*)(ws + alloc((size_t)EMBED * HIDDEN * 2));
    int*    csr = (int*)   (ws + alloc((size_t)vocab * CAP * 4));
    int*    cnt = (int*)   (ws + alloc((size_t)vocab * 4));

    int zeroBlocks = (vocab + 255) / 256;                         // 197
    prep_kernel<<<128 + zeroBlocks, 256, 0, stream>>>(w1, w2, W1t, W2t, cnt, vocab);

    bucket_kernel<<<(nk + 255) / 256, 256, 0, stream>>>(bi, bj, cnt, csr, nk);

    mlp_mfma_kernel<<<ntok / TB, 512, 0, stream>>>(tokens, table, cnt, csr,
                                                   W1t, W2t, b1, b2, out);
}